// Round 14
// baseline (255.470 us; speedup 1.0000x reference)
//
#include <hip/hip_runtime.h>
#include <hip/hip_fp16.h>

#define DF 96
#define BN_EPS 1e-3f
#define MAXNB 1024
#define PTILE 2048     // partition tile: 391 blocks at E=800k (occupancy)
#define HTILE 2048     // hist tile

// ---------------- GEMM: C[N,96] = prologue(A)[N,96] @ W[96,96] ----------------
// Used for layer 1 (x fp32 -> Hh fp16) and the fp32 fallback path.
template<bool FUSE_BN, bool HALF_IN, bool HALF_OUT>
__global__ __launch_bounds__(192) void gemm_bn_kernel(
    const void* __restrict__ Ain, const float* __restrict__ W,
    const float* __restrict__ g, const float* __restrict__ b,
    const float* __restrict__ m, const float* __restrict__ v,
    void* __restrict__ Cout, int N)
{
    __shared__ __half2 sWh[96 * 48];   // 96x96 W as half2 (18.4 KB)
    __shared__ float   sA[64 * 100];
    __shared__ float   sS[96], sT[96];

    const int tid  = threadIdx.x;
    const int row0 = blockIdx.x * 64;

    if (FUSE_BN && tid < 96) {
        float s = g[tid] * rsqrtf(v[tid] + BN_EPS);
        sS[tid] = s;
        sT[tid] = b[tid] - m[tid] * s;
    }
    {
        const float4* Wv = reinterpret_cast<const float4*>(W);
        #pragma unroll
        for (int i = 0; i < 12; ++i) {
            int f = tid + 192 * i;
            float4 w = Wv[f];
            sWh[2 * f]     = __floats2half2_rn(w.x, w.y);
            sWh[2 * f + 1] = __floats2half2_rn(w.z, w.w);
        }
    }
    __syncthreads();

    #pragma unroll
    for (int i = 0; i < 8; ++i) {
        int f   = tid + 192 * i;
        int row = f / 24;
        int cc  = (f % 24) * 4;
        int gr  = row0 + row;
        float4 val = make_float4(0.f, 0.f, 0.f, 0.f);
        if (gr < N) {
            if (HALF_IN) {
                const __half* Ah = (const __half*)Ain + (size_t)gr * DF + cc;
                float2 raw = *reinterpret_cast<const float2*>(Ah);
                union { float2 f2; __half2 h[2]; } u; u.f2 = raw;
                float2 lo = __half22float2(u.h[0]);
                float2 hi = __half22float2(u.h[1]);
                val = make_float4(lo.x, lo.y, hi.x, hi.y);
            } else {
                val = *reinterpret_cast<const float4*>(
                          (const float*)Ain + (size_t)gr * DF + cc);
            }
            if (FUSE_BN) {
                float* p = &val.x;
                #pragma unroll
                for (int j = 0; j < 4; ++j) {
                    float x_ = p[j];
                    x_ = x_ > 0.f ? x_ : 0.f;
                    p[j] = x_ * sS[cc + j] + sT[cc + j];
                }
            }
        }
        *reinterpret_cast<float4*>(sA + row * 100 + cc) = val;
    }
    __syncthreads();

    const int tx = tid % 24, ty = tid / 24;
    float acc[8][4];
    #pragma unroll
    for (int i = 0; i < 8; ++i)
        for (int j = 0; j < 4; ++j) acc[i][j] = 0.f;

    for (int k = 0; k < 96; ++k) {
        float2 wa = __half22float2(sWh[k * 48 + tx * 2]);
        float2 wb = __half22float2(sWh[k * 48 + tx * 2 + 1]);
        #pragma unroll
        for (int i = 0; i < 8; ++i) {
            float a = sA[(ty + 8 * i) * 100 + k];
            acc[i][0] += a * wa.x;
            acc[i][1] += a * wa.y;
            acc[i][2] += a * wb.x;
            acc[i][3] += a * wb.y;
        }
    }
    const int c0 = tx * 4;
    #pragma unroll
    for (int i = 0; i < 8; ++i) {
        int gr = row0 + ty + 8 * i;
        if (gr >= N) continue;
        if (HALF_OUT) {
            __half* C = (__half*)Cout;
            ushort4 u;
            u.x = __half_as_ushort(__float2half_rn(acc[i][0]));
            u.y = __half_as_ushort(__float2half_rn(acc[i][1]));
            u.z = __half_as_ushort(__float2half_rn(acc[i][2]));
            u.w = __half_as_ushort(__float2half_rn(acc[i][3]));
            *reinterpret_cast<ushort4*>(C + (size_t)gr * DF + c0) = u;
        } else {
            float* C = (float*)Cout;
            *reinterpret_cast<float4*>(C + (size_t)gr * DF + c0) =
                make_float4(acc[i][0], acc[i][1], acc[i][2], acc[i][3]);
        }
    }
}

// ---------------- CSR build (bucket = dst >> 6, low write-amp) ---------------
__global__ void zero_kernel(int* __restrict__ p, int n)
{
    int i = blockIdx.x * blockDim.x + threadIdx.x;
    if (i < n) p[i] = 0;
}

// convert W2,W3 (fp32) to fp16 once (for the fused kernels)
__global__ void convw_kernel(const float* __restrict__ w2,
                             const float* __restrict__ w3,
                             __half* __restrict__ o2, __half* __restrict__ o3)
{
    int i = blockIdx.x * blockDim.x + threadIdx.x;
    if (i < 96 * 96) {
        o2[i] = __float2half_rn(w2[i]);
        o3[i] = __float2half_rn(w3[i]);
    }
}

__global__ __launch_bounds__(256) void bucket_hist_kernel(
    const int* __restrict__ dst, int* __restrict__ bcnt, int E, int NB)
{
    __shared__ int lc[MAXNB];
    for (int i = threadIdx.x; i < NB; i += 256) lc[i] = 0;
    __syncthreads();
    int base = blockIdx.x * HTILE;
    #pragma unroll
    for (int j = 0; j < HTILE / 256; ++j) {
        int i = base + j * 256 + threadIdx.x;
        if (i < E) atomicAdd(&lc[dst[i] >> 6], 1);
    }
    __syncthreads();
    for (int i = threadIdx.x; i < NB; i += 256) {
        int c = lc[i];
        if (c) atomicAdd(&bcnt[i], c);
    }
}

__global__ __launch_bounds__(256) void bucket_scan_kernel(
    int* __restrict__ bbase, int* __restrict__ bcur, int NB)
{
    __shared__ int wsum[4];
    int t = threadIdx.x, lane = t & 63, wv = t >> 6;
    int vals[4], s = 0;
    #pragma unroll
    for (int j = 0; j < 4; ++j) {
        int idx = t * 4 + j;
        vals[j] = (idx < NB) ? bcur[idx] : 0;
        s += vals[j];
    }
    int inc = s;
    #pragma unroll
    for (int o = 1; o < 64; o <<= 1) {
        int u = __shfl_up(inc, o);
        if (lane >= o) inc += u;
    }
    int excl = inc - s;
    if (lane == 63) wsum[wv] = inc;
    __syncthreads();
    if (t == 0) {
        int run = 0;
        #pragma unroll
        for (int j = 0; j < 4; ++j) { int vv = wsum[j]; wsum[j] = run; run += vv; }
    }
    __syncthreads();
    int off = wsum[wv] + excl;
    #pragma unroll
    for (int j = 0; j < 4; ++j) {
        int idx = t * 4 + j;
        if (idx < NB) { bbase[idx] = off; bcur[idx] = off; off += vals[j]; }
    }
}

__global__ __launch_bounds__(256) void partition_kernel(
    const int* __restrict__ src, const int* __restrict__ dst,
    const float* __restrict__ ew, int* __restrict__ bcur,
    int2* __restrict__ ebufA, int E, int NB)
{
    __shared__ int lc[MAXNB];
    for (int i = threadIdx.x; i < NB; i += 256) lc[i] = 0;
    __syncthreads();
    int base = blockIdx.x * PTILE;
    #pragma unroll
    for (int j = 0; j < PTILE / 256; ++j) {
        int i = base + j * 256 + threadIdx.x;
        if (i < E) atomicAdd(&lc[dst[i] >> 6], 1);
    }
    __syncthreads();
    for (int i = threadIdx.x; i < NB; i += 256) {
        int c = lc[i];
        lc[i] = c ? atomicAdd(&bcur[i], c) : 0;
    }
    __syncthreads();
    #pragma unroll
    for (int j = 0; j < PTILE / 256; ++j) {
        int i = base + j * 256 + threadIdx.x;
        if (i < E) {
            int d   = dst[i];
            int bkt = d >> 6;
            int pos = atomicAdd(&lc[bkt], 1);
            ebufA[pos] = make_int2(src[i] | ((d & 63) << 26), __float_as_int(ew[i]));
        }
    }
}

__global__ __launch_bounds__(256) void csr_bucket_kernel(
    const int2* __restrict__ ebufA, const int* __restrict__ bbase,
    const int* __restrict__ bcur, int2* __restrict__ pairs,
    int* __restrict__ row_ptr, int N, int E, int NB)
{
    __shared__ int lc[64];
    int t   = threadIdx.x;
    int bkt = blockIdx.x;
    int e0  = bbase[bkt];
    int cnt = bcur[bkt] - e0;

    if (t < 64) lc[t] = 0;
    __syncthreads();
    for (int i = t; i < cnt; i += 256)
        atomicAdd(&lc[((unsigned)ebufA[e0 + i].x) >> 26], 1);
    __syncthreads();
    if (t < 64) {
        int v   = lc[t];
        int inc = v;
        #pragma unroll
        for (int o = 1; o < 64; o <<= 1) {
            int u = __shfl_up(inc, o);
            if (t >= o) inc += u;
        }
        int excl = inc - v;
        int node = (bkt << 6) + t;
        if (node < N) row_ptr[node] = e0 + excl;
        lc[t] = excl;
    }
    __syncthreads();
    for (int i = t; i < cnt; i += 256) {
        int2 p = ebufA[e0 + i];
        unsigned px = (unsigned)p.x;
        int pos = atomicAdd(&lc[px >> 26], 1);
        pairs[e0 + pos] = make_int2((int)(px & 0x03FFFFFFu), p.y);
    }
    if (bkt == NB - 1 && t == 0) row_ptr[N] = E;
}

// ---------------- Gather (standalone; final layer + fp32 path) --------------
template<bool FINAL, bool HALF, bool OHALF>
__global__ __launch_bounds__(192) void gather_kernel(
    const void* __restrict__ hbuf, const int2* __restrict__ pairs,
    const int* __restrict__ row_ptr, void* __restrict__ out,
    const float* __restrict__ xres,
    const float* __restrict__ g, const float* __restrict__ b,
    const float* __restrict__ m, const float* __restrict__ v, int N)
{
    __shared__ __attribute__((aligned(16))) float sS[96];
    __shared__ __attribute__((aligned(16))) float sT[96];
    if (FINAL) {
        int t = threadIdx.x;
        if (t < 96) {
            float s = g[t] * rsqrtf(v[t] + BN_EPS);
            sS[t] = s;
            sT[t] = b[t] - m[t] * s;
        }
        __syncthreads();
    }
    int node = blockIdx.x * 8 + threadIdx.x / 24;
    int q    = threadIdx.x % 24;
    if (node >= N) return;

    auto ld = [&](int srcR) -> float4 {
        if (HALF) {
            const __half* hp = (const __half*)hbuf + (size_t)srcR * DF + q * 4;
            float2 raw = *reinterpret_cast<const float2*>(hp);
            union { float2 f; __half2 h[2]; } u; u.f = raw;
            float2 lo = __half22float2(u.h[0]);
            float2 hi = __half22float2(u.h[1]);
            return make_float4(lo.x, lo.y, hi.x, hi.y);
        } else {
            return *(reinterpret_cast<const float4*>(
                        (const float*)hbuf + (size_t)srcR * DF) + q);
        }
    };

    int e   = row_ptr[node];
    int end = row_ptr[node + 1];
    float ax = 0.f, ay = 0.f, az = 0.f, aw = 0.f;

    auto fma1 = [&](int sr, float w) {
        float4 hv = ld(sr);
        ax = fmaf(w, hv.x, ax); ay = fmaf(w, hv.y, ay);
        az = fmaf(w, hv.z, az); aw = fmaf(w, hv.w, aw);
    };

    if (e < end && (e & 1)) {
        int2 p = pairs[e];
        fma1(p.x, __int_as_float(p.y));
        ++e;
    }
    const int4* p2 = reinterpret_cast<const int4*>(pairs);

    for (; e + 8 <= end; e += 8) {
        int h0 = e >> 1;
        int4 q0 = p2[h0 + 0];
        int4 q1 = p2[h0 + 1];
        int4 q2 = p2[h0 + 2];
        int4 q3 = p2[h0 + 3];
        float4 v0 = ld(q0.x), v1 = ld(q0.z);
        float4 v2 = ld(q1.x), v3 = ld(q1.z);
        float4 v4 = ld(q2.x), v5 = ld(q2.z);
        float4 v6 = ld(q3.x), v7 = ld(q3.z);
        float w0 = __int_as_float(q0.y), w1 = __int_as_float(q0.w);
        float w2 = __int_as_float(q1.y), w3 = __int_as_float(q1.w);
        float w4 = __int_as_float(q2.y), w5 = __int_as_float(q2.w);
        float w6 = __int_as_float(q3.y), w7 = __int_as_float(q3.w);
        ax = fmaf(w0, v0.x, ax); ay = fmaf(w0, v0.y, ay);
        az = fmaf(w0, v0.z, az); aw = fmaf(w0, v0.w, aw);
        ax = fmaf(w1, v1.x, ax); ay = fmaf(w1, v1.y, ay);
        az = fmaf(w1, v1.z, az); aw = fmaf(w1, v1.w, aw);
        ax = fmaf(w2, v2.x, ax); ay = fmaf(w2, v2.y, ay);
        az = fmaf(w2, v2.z, az); aw = fmaf(w2, v2.w, aw);
        ax = fmaf(w3, v3.x, ax); ay = fmaf(w3, v3.y, ay);
        az = fmaf(w3, v3.z, az); aw = fmaf(w3, v3.w, aw);
        ax = fmaf(w4, v4.x, ax); ay = fmaf(w4, v4.y, ay);
        az = fmaf(w4, v4.z, az); aw = fmaf(w4, v4.w, aw);
        ax = fmaf(w5, v5.x, ax); ay = fmaf(w5, v5.y, ay);
        az = fmaf(w5, v5.z, az); aw = fmaf(w5, v5.w, aw);
        ax = fmaf(w6, v6.x, ax); ay = fmaf(w6, v6.y, ay);
        az = fmaf(w6, v6.z, az); aw = fmaf(w6, v6.w, aw);
        ax = fmaf(w7, v7.x, ax); ay = fmaf(w7, v7.y, ay);
        az = fmaf(w7, v7.z, az); aw = fmaf(w7, v7.w, aw);
    }
    for (; e + 2 <= end; e += 2) {
        int4 q0 = p2[e >> 1];
        float4 v0 = ld(q0.x), v1 = ld(q0.z);
        float w0 = __int_as_float(q0.y), w1 = __int_as_float(q0.w);
        ax = fmaf(w0, v0.x, ax); ay = fmaf(w0, v0.y, ay);
        az = fmaf(w0, v0.z, az); aw = fmaf(w0, v0.w, aw);
        ax = fmaf(w1, v1.x, ax); ay = fmaf(w1, v1.y, ay);
        az = fmaf(w1, v1.z, az); aw = fmaf(w1, v1.w, aw);
    }
    if (e < end) {
        int2 p = pairs[e];
        fma1(p.x, __int_as_float(p.y));
    }

    size_t o = (size_t)node * DF + q * 4;
    if (FINAL) {
        int c = q * 4;
        float* of = (float*)out;
        float4 xv = *reinterpret_cast<const float4*>(xres + o);
        float4 s4 = *reinterpret_cast<const float4*>(sS + c);
        float4 t4 = *reinterpret_cast<const float4*>(sT + c);
        float4 r;
        r.x = fmaf(fmaxf(ax, 0.f), s4.x, t4.x) + xv.x;
        r.y = fmaf(fmaxf(ay, 0.f), s4.y, t4.y) + xv.y;
        r.z = fmaf(fmaxf(az, 0.f), s4.z, t4.z) + xv.z;
        r.w = fmaf(fmaxf(aw, 0.f), s4.w, t4.w) + xv.w;
        *reinterpret_cast<float4*>(of + o) = r;
    } else if (OHALF) {
        __half* oh = (__half*)out;
        ushort4 u;
        u.x = __half_as_ushort(__float2half_rn(ax));
        u.y = __half_as_ushort(__float2half_rn(ay));
        u.z = __half_as_ushort(__float2half_rn(az));
        u.w = __half_as_ushort(__float2half_rn(aw));
        *reinterpret_cast<ushort4*>(oh + o) = u;
    } else {
        *reinterpret_cast<float4*>((float*)out + o) =
            make_float4(ax, ay, az, aw);
    }
}

// ---------------- Fused: gather + ReLU + BN(L) + GEMM(W[L+1]) -> h fp16 ------
// r12 structure; r13 packed-hfma2 epilogue; r14: W read DIRECTLY from global
// in the epilogue (18.4KB, L1/L2-resident across all blocks) instead of LDS
// staging. LDS 22.5KB -> ~4KB => blocks/CU 7 -> 10 (30 waves/CU) for latency
// hiding of both the random gather and the epilogue (r13 counters: occ 45%,
// VALUBusy 34%, fetch 1.35TB/s -- latency-bound, wants occupancy).
__global__ __launch_bounds__(192) void fused_gather_gemm_kernel(
    const __half* __restrict__ hin, const int2* __restrict__ pairs,
    const int* __restrict__ row_ptr, const __half* __restrict__ Wh,
    const float* __restrict__ g, const float* __restrict__ b,
    const float* __restrict__ m, const float* __restrict__ v,
    __half* __restrict__ hout, int N)
{
    __shared__ float sRow[8][100];                           // 3.2 KB (pad 100)
    __shared__ float sS[96], sT[96];

    const int t = threadIdx.x;
    if (t < 96) {
        float s = g[t] * rsqrtf(v[t] + BN_EPS);
        sS[t] = s;
        sT[t] = b[t] - m[t] * s;
    }

    const int  node  = t / 24;
    const int  q     = t % 24;
    const int  nodeg = blockIdx.x * 8 + node;
    const bool valid = nodeg < N;

    float ax = 0.f, ay = 0.f, az = 0.f, aw = 0.f;
    if (valid) {
        auto ld = [&](int srcR) -> float4 {
            const __half* hp = hin + (size_t)srcR * DF + q * 4;
            float2 raw = *reinterpret_cast<const float2*>(hp);
            union { float2 f; __half2 h[2]; } u; u.f = raw;
            float2 lo = __half22float2(u.h[0]);
            float2 hi = __half22float2(u.h[1]);
            return make_float4(lo.x, lo.y, hi.x, hi.y);
        };
        int e   = row_ptr[nodeg];
        int end = row_ptr[nodeg + 1];
        if (e < end && (e & 1)) {
            int2 p = pairs[e];
            float4 hv = ld(p.x);
            float w = __int_as_float(p.y);
            ax = fmaf(w, hv.x, ax); ay = fmaf(w, hv.y, ay);
            az = fmaf(w, hv.z, az); aw = fmaf(w, hv.w, aw);
            ++e;
        }
        const int4* p2 = reinterpret_cast<const int4*>(pairs);
        for (; e + 8 <= end; e += 8) {
            int h0 = e >> 1;
            int4 q0 = p2[h0 + 0];
            int4 q1 = p2[h0 + 1];
            int4 q2 = p2[h0 + 2];
            int4 q3 = p2[h0 + 3];
            float4 v0 = ld(q0.x), v1 = ld(q0.z);
            float4 v2 = ld(q1.x), v3 = ld(q1.z);
            float4 v4 = ld(q2.x), v5 = ld(q2.z);
            float4 v6 = ld(q3.x), v7 = ld(q3.z);
            float w0 = __int_as_float(q0.y), w1 = __int_as_float(q0.w);
            float w2 = __int_as_float(q1.y), w3 = __int_as_float(q1.w);
            float w4 = __int_as_float(q2.y), w5 = __int_as_float(q2.w);
            float w6 = __int_as_float(q3.y), w7 = __int_as_float(q3.w);
            ax = fmaf(w0, v0.x, ax); ay = fmaf(w0, v0.y, ay);
            az = fmaf(w0, v0.z, az); aw = fmaf(w0, v0.w, aw);
            ax = fmaf(w1, v1.x, ax); ay = fmaf(w1, v1.y, ay);
            az = fmaf(w1, v1.z, az); aw = fmaf(w1, v1.w, aw);
            ax = fmaf(w2, v2.x, ax); ay = fmaf(w2, v2.y, ay);
            az = fmaf(w2, v2.z, az); aw = fmaf(w2, v2.w, aw);
            ax = fmaf(w3, v3.x, ax); ay = fmaf(w3, v3.y, ay);
            az = fmaf(w3, v3.z, az); aw = fmaf(w3, v3.w, aw);
            ax = fmaf(w4, v4.x, ax); ay = fmaf(w4, v4.y, ay);
            az = fmaf(w4, v4.z, az); aw = fmaf(w4, v4.w, aw);
            ax = fmaf(w5, v5.x, ax); ay = fmaf(w5, v5.y, ay);
            az = fmaf(w5, v5.z, az); aw = fmaf(w5, v5.w, aw);
            ax = fmaf(w6, v6.x, ax); ay = fmaf(w6, v6.y, ay);
            az = fmaf(w6, v6.z, az); aw = fmaf(w6, v6.w, aw);
            ax = fmaf(w7, v7.x, ax); ay = fmaf(w7, v7.y, ay);
            az = fmaf(w7, v7.z, az); aw = fmaf(w7, v7.w, aw);
        }
        for (; e + 2 <= end; e += 2) {
            int4 q0 = p2[e >> 1];
            float4 v0 = ld(q0.x), v1 = ld(q0.z);
            float w0 = __int_as_float(q0.y), w1 = __int_as_float(q0.w);
            ax = fmaf(w0, v0.x, ax); ay = fmaf(w0, v0.y, ay);
            az = fmaf(w0, v0.z, az); aw = fmaf(w0, v0.w, aw);
            ax = fmaf(w1, v1.x, ax); ay = fmaf(w1, v1.y, ay);
            az = fmaf(w1, v1.z, az); aw = fmaf(w1, v1.w, aw);
        }
        if (e < end) {
            int2 p = pairs[e];
            float4 hv = ld(p.x);
            float w = __int_as_float(p.y);
            ax = fmaf(w, hv.x, ax); ay = fmaf(w, hv.y, ay);
            az = fmaf(w, hv.z, az); aw = fmaf(w, hv.w, aw);
        }
    }
    __syncthreads();   // sS/sT staged; all threads present (no returns)

    // epilogue 1: relu + BN(L) -> sRow
    if (valid) {
        int c = q * 4;
        sRow[node][c + 0] = fmaf(fmaxf(ax, 0.f), sS[c + 0], sT[c + 0]);
        sRow[node][c + 1] = fmaf(fmaxf(ay, 0.f), sS[c + 1], sT[c + 1]);
        sRow[node][c + 2] = fmaf(fmaxf(az, 0.f), sS[c + 2], sT[c + 2]);
        sRow[node][c + 3] = fmaf(fmaxf(aw, 0.f), sS[c + 3], sT[c + 3]);
    }
    __syncthreads();

    // epilogue 2: GEMM row -> hout fp16, packed-fp16 accumulation.
    // W read directly from global (8B/thread/k, wave touches one 192B W-row
    // per k -> L1-resident).
    __half2 o01 = __floats2half2_rn(0.f, 0.f);
    __half2 o23 = o01;
    const __half* wrow = Wh + q * 4;
    for (int k = 0; k < 96; ++k) {
        const __half2* wp = reinterpret_cast<const __half2*>(wrow + k * 96);
        __half2 w01 = wp[0];
        __half2 w23 = wp[1];
        __half2 a2  = __float2half2_rn(sRow[node][k]);
        o01 = __hfma2(a2, w01, o01);
        o23 = __hfma2(a2, w23, o23);
    }
    if (valid) {
        uint2 u;
        u.x = *reinterpret_cast<const unsigned*>(&o01);
        u.y = *reinterpret_cast<const unsigned*>(&o23);
        *reinterpret_cast<uint2*>(hout + (size_t)nodeg * DF + q * 4) = u;
    }
}

// ---------------- last-resort fallback: atomic scatter -----------------------
__global__ __launch_bounds__(256) void scatter_kernel(
    const float* __restrict__ h, const int* __restrict__ src,
    const int* __restrict__ dst, const float* __restrict__ ew,
    float* __restrict__ agg, int E)
{
    long long t = (long long)blockIdx.x * blockDim.x + threadIdx.x;
    if (t >= (long long)E * 24) return;
    int e  = (int)(t / 24);
    int cc = (int)(t % 24) * 4;
    int s  = src[e];
    int d  = dst[e];
    float w = ew[e];
    float4 hv = *reinterpret_cast<const float4*>(h + (size_t)s * DF + cc);
    float* out = agg + (size_t)d * DF + cc;
    atomicAdd(out + 0, w * hv.x);
    atomicAdd(out + 1, w * hv.y);
    atomicAdd(out + 2, w * hv.z);
    atomicAdd(out + 3, w * hv.w);
}

__global__ __launch_bounds__(256) void final_kernel(
    const float* __restrict__ agg, const float* __restrict__ x,
    const float* __restrict__ g, const float* __restrict__ b,
    const float* __restrict__ m, const float* __restrict__ v,
    float* __restrict__ out, int total4)
{
    int i = blockIdx.x * blockDim.x + threadIdx.x;
    if (i >= total4) return;
    int cc = (i % 24) * 4;
    float4 a4 = reinterpret_cast<const float4*>(agg)[i];
    float4 x4 = reinterpret_cast<const float4*>(x)[i];
    float* pa = &a4.x;
    const float* px = &x4.x;
    float4 o;
    float* po = &o.x;
    #pragma unroll
    for (int j = 0; j < 4; ++j) {
        int c = cc + j;
        float s  = g[c] * rsqrtf(v[c] + BN_EPS);
        float tt = b[c] - m[c] * s;
        float a  = pa[j] > 0.f ? pa[j] : 0.f;
        po[j] = a * s + tt + px[j];
    }
    reinterpret_cast<float4*>(out)[i] = o;
}

extern "C" void kernel_launch(void* const* d_in, const int* in_sizes, int n_in,
                              void* d_out, int out_size, void* d_ws, size_t ws_size,
                              hipStream_t stream)
{
    const float* x    = (const float*)d_in[0];
    const int*   esrc = (const int*)d_in[1];
    const int*   edst = (const int*)d_in[2];
    const float* ew   = (const float*)d_in[3];
    const float* w1   = (const float*)d_in[4];
    const float* w2   = (const float*)d_in[5];
    const float* w3   = (const float*)d_in[6];
    const float* g1 = (const float*)d_in[7],  *b1 = (const float*)d_in[8];
    const float* m1 = (const float*)d_in[9],  *v1 = (const float*)d_in[10];
    const float* g2 = (const float*)d_in[11], *b2 = (const float*)d_in[12];
    const float* m2 = (const float*)d_in[13], *v2 = (const float*)d_in[14];
    const float* g3 = (const float*)d_in[15], *b3 = (const float*)d_in[16];
    const float* m3 = (const float*)d_in[17], *v3 = (const float*)d_in[18];

    const int N  = in_sizes[0] / DF;   // 50000
    const int E  = in_sizes[1];        // 800000
    const int NB = (N + 63) >> 6;      // 782 buckets
    const size_t nbytes = (size_t)N * DF * sizeof(float);
    const size_t hh_bytes = (size_t)N * DF * 2;
    const size_t wh_bytes = (size_t)96 * 96 * 2;

    float* B = (float*)d_out;

    auto up = [](size_t s) { return (s + 255) & ~(size_t)255; };
    size_t off_agg   = 0;                               // fp32 agg OR fp16 h-buf B
    size_t off_pairs = off_agg   + up(nbytes);
    size_t off_rptr  = off_pairs + up((size_t)E * 8);
    size_t off_bbase = off_rptr  + up(((size_t)N + 1) * 4);
    size_t off_bcur  = off_bbase + up((size_t)NB * 4);
    size_t off_wh2   = off_bcur  + up((size_t)NB * 4);
    size_t off_wh3   = off_wh2   + up(wh_bytes);
    size_t off_ebufA = off_wh3   + up(wh_bytes);        // ebufA last; Hh_a aliases
    size_t need_f32  = off_ebufA + up((size_t)E * 8);
    size_t ovl       = (size_t)E * 8 > hh_bytes ? (size_t)E * 8 : hh_bytes;
    size_t need_f16  = off_ebufA + up(ovl);

    char*  ws = (char*)d_ws;
    float* A  = (float*)(ws + off_agg);

    const int gemm_grid = (N + 63) / 64;
    const bool ok = (NB <= MAXNB) && (N < (1 << 26)) && (ws_size >= need_f32);

    if (ok) {
        int2*   ebufA  = (int2*)(ws + off_ebufA);
        __half* HhA    = (__half*)(ws + off_ebufA);   // alias: ebufA dead after csr
        __half* HhB    = (__half*)(ws + off_agg);     // second fp16 h buffer
        __half* Wh2    = (__half*)(ws + off_wh2);
        __half* Wh3    = (__half*)(ws + off_wh3);
        int2*   pairs  = (int2*)(ws + off_pairs);
        int*    rowptr = (int*) (ws + off_rptr);
        int*    bbase  = (int*) (ws + off_bbase);
        int*    bcur   = (int*) (ws + off_bcur);
        const bool half_h = (ws_size >= need_f16);

        // ---- CSR build (once): zero -> hist -> scan -> partition -> sort ----
        zero_kernel<<<(NB + 255) / 256, 256, 0, stream>>>(bcur, NB);
        bucket_hist_kernel<<<(E + HTILE - 1) / HTILE, 256, 0, stream>>>(
            edst, bcur, E, NB);
        bucket_scan_kernel<<<1, 256, 0, stream>>>(bbase, bcur, NB);
        partition_kernel<<<(E + PTILE - 1) / PTILE, 256, 0, stream>>>(
            esrc, edst, ew, bcur, ebufA, E, NB);
        csr_bucket_kernel<<<NB, 256, 0, stream>>>(
            ebufA, bbase, bcur, pairs, rowptr, N, E, NB);

        const int ggrid = (N + 7) / 8;

        if (half_h) {
            convw_kernel<<<(96 * 96 + 255) / 256, 256, 0, stream>>>(
                w2, w3, Wh2, Wh3);
            // layer 1: x -> HhA (over dead ebufA)
            gemm_bn_kernel<false, false, true><<<gemm_grid, 192, 0, stream>>>(
                x, w1, nullptr, nullptr, nullptr, nullptr, HhA, N);
            // layer 2 fused: gather(HhA)+BN1+GEMM(W2) -> HhB
            fused_gather_gemm_kernel<<<ggrid, 192, 0, stream>>>(
                HhA, pairs, rowptr, Wh2, g1, b1, m1, v1, HhB, N);
            // layer 3 fused: gather(HhB)+BN2+GEMM(W3) -> HhA
            fused_gather_gemm_kernel<<<ggrid, 192, 0, stream>>>(
                HhB, pairs, rowptr, Wh3, g2, b2, m2, v2, HhA, N);
            // final: gather(HhA) + BN3 + residual -> d_out
            gather_kernel<true, true, false><<<ggrid, 192, 0, stream>>>(
                HhA, pairs, rowptr, B, x, g3, b3, m3, v3, N);
        } else {
            // fp32 everything; h in d_out (proven round-5 pipeline)
            gemm_bn_kernel<false, false, false><<<gemm_grid, 192, 0, stream>>>(
                x, w1, nullptr, nullptr, nullptr, nullptr, B, N);
            gather_kernel<false, false, false><<<ggrid, 192, 0, stream>>>(
                B, pairs, rowptr, A, nullptr, nullptr, nullptr, nullptr, nullptr, N);
            gemm_bn_kernel<true, false, false><<<gemm_grid, 192, 0, stream>>>(
                A, w2, g1, b1, m1, v1, B, N);
            gather_kernel<false, false, false><<<ggrid, 192, 0, stream>>>(
                B, pairs, rowptr, A, nullptr, nullptr, nullptr, nullptr, nullptr, N);
            gemm_bn_kernel<true, false, false><<<gemm_grid, 192, 0, stream>>>(
                A, w3, g2, b2, m2, v2, A, N);
            gather_kernel<true, false, false><<<ggrid, 192, 0, stream>>>(
                A, pairs, rowptr, B, x, g3, b3, m3, v3, N);
        }
    } else {
        // last-resort: atomic scatter path
        const long long st     = (long long)E * 24;
        const int scatter_grid = (int)((st + 255) / 256);
        const int total4       = N * 24;
        const int final_grid   = (total4 + 255) / 256;

        hipMemsetAsync(A, 0, nbytes, stream);
        gemm_bn_kernel<false, false, false><<<gemm_grid, 192, 0, stream>>>(
            x, w1, nullptr, nullptr, nullptr, nullptr, B, N);
        scatter_kernel<<<scatter_grid, 256, 0, stream>>>(B, esrc, edst, ew, A, E);

        gemm_bn_kernel<true, false, false><<<gemm_grid, 192, 0, stream>>>(
            A, w2, g1, b1, m1, v1, B, N);
        hipMemsetAsync(A, 0, nbytes, stream);
        scatter_kernel<<<scatter_grid, 256, 0, stream>>>(B, esrc, edst, ew, A, E);

        gemm_bn_kernel<true, false, false><<<gemm_grid, 192, 0, stream>>>(
            A, w3, g2, b2, m2, v2, B, N);
        hipMemsetAsync(A, 0, nbytes, stream);
        scatter_kernel<<<scatter_grid, 256, 0, stream>>>(B, esrc, edst, ew, A, E);

        final_kernel<<<final_grid, 256, 0, stream>>>(
            A, x, g3, b3, m3, v3, (float*)d_out, total4);
    }
}

// Round 15
// 192.919 us; speedup vs baseline: 1.3242x; 1.3242x over previous
//
#include <hip/hip_runtime.h>
#include <hip/hip_fp16.h>

#define DF 96
#define BN_EPS 1e-3f
#define MAXNB 1024
#define PTILE 2048     // partition tile: 391 blocks at E=800k (occupancy)
#define HTILE 2048     // hist tile

// ---------------- GEMM: C[N,96] = prologue(A)[N,96] @ W[96,96] ----------------
// Used for layer 1 (x fp32 -> Hh fp16) and the fp32 fallback path.
template<bool FUSE_BN, bool HALF_IN, bool HALF_OUT>
__global__ __launch_bounds__(192) void gemm_bn_kernel(
    const void* __restrict__ Ain, const float* __restrict__ W,
    const float* __restrict__ g, const float* __restrict__ b,
    const float* __restrict__ m, const float* __restrict__ v,
    void* __restrict__ Cout, int N)
{
    __shared__ __half2 sWh[96 * 48];   // 96x96 W as half2 (18.4 KB)
    __shared__ float   sA[64 * 100];
    __shared__ float   sS[96], sT[96];

    const int tid  = threadIdx.x;
    const int row0 = blockIdx.x * 64;

    if (FUSE_BN && tid < 96) {
        float s = g[tid] * rsqrtf(v[tid] + BN_EPS);
        sS[tid] = s;
        sT[tid] = b[tid] - m[tid] * s;
    }
    {
        const float4* Wv = reinterpret_cast<const float4*>(W);
        #pragma unroll
        for (int i = 0; i < 12; ++i) {
            int f = tid + 192 * i;
            float4 w = Wv[f];
            sWh[2 * f]     = __floats2half2_rn(w.x, w.y);
            sWh[2 * f + 1] = __floats2half2_rn(w.z, w.w);
        }
    }
    __syncthreads();

    #pragma unroll
    for (int i = 0; i < 8; ++i) {
        int f   = tid + 192 * i;
        int row = f / 24;
        int cc  = (f % 24) * 4;
        int gr  = row0 + row;
        float4 val = make_float4(0.f, 0.f, 0.f, 0.f);
        if (gr < N) {
            if (HALF_IN) {
                const __half* Ah = (const __half*)Ain + (size_t)gr * DF + cc;
                float2 raw = *reinterpret_cast<const float2*>(Ah);
                union { float2 f2; __half2 h[2]; } u; u.f2 = raw;
                float2 lo = __half22float2(u.h[0]);
                float2 hi = __half22float2(u.h[1]);
                val = make_float4(lo.x, lo.y, hi.x, hi.y);
            } else {
                val = *reinterpret_cast<const float4*>(
                          (const float*)Ain + (size_t)gr * DF + cc);
            }
            if (FUSE_BN) {
                float* p = &val.x;
                #pragma unroll
                for (int j = 0; j < 4; ++j) {
                    float x_ = p[j];
                    x_ = x_ > 0.f ? x_ : 0.f;
                    p[j] = x_ * sS[cc + j] + sT[cc + j];
                }
            }
        }
        *reinterpret_cast<float4*>(sA + row * 100 + cc) = val;
    }
    __syncthreads();

    const int tx = tid % 24, ty = tid / 24;
    float acc[8][4];
    #pragma unroll
    for (int i = 0; i < 8; ++i)
        for (int j = 0; j < 4; ++j) acc[i][j] = 0.f;

    for (int k = 0; k < 96; ++k) {
        float2 wa = __half22float2(sWh[k * 48 + tx * 2]);
        float2 wb = __half22float2(sWh[k * 48 + tx * 2 + 1]);
        #pragma unroll
        for (int i = 0; i < 8; ++i) {
            float a = sA[(ty + 8 * i) * 100 + k];
            acc[i][0] += a * wa.x;
            acc[i][1] += a * wa.y;
            acc[i][2] += a * wb.x;
            acc[i][3] += a * wb.y;
        }
    }
    const int c0 = tx * 4;
    #pragma unroll
    for (int i = 0; i < 8; ++i) {
        int gr = row0 + ty + 8 * i;
        if (gr >= N) continue;
        if (HALF_OUT) {
            __half* C = (__half*)Cout;
            ushort4 u;
            u.x = __half_as_ushort(__float2half_rn(acc[i][0]));
            u.y = __half_as_ushort(__float2half_rn(acc[i][1]));
            u.z = __half_as_ushort(__float2half_rn(acc[i][2]));
            u.w = __half_as_ushort(__float2half_rn(acc[i][3]));
            *reinterpret_cast<ushort4*>(C + (size_t)gr * DF + c0) = u;
        } else {
            float* C = (float*)Cout;
            *reinterpret_cast<float4*>(C + (size_t)gr * DF + c0) =
                make_float4(acc[i][0], acc[i][1], acc[i][2], acc[i][3]);
        }
    }
}

// ---------------- CSR build (bucket = dst >> 6, low write-amp) ---------------
__global__ void zero_kernel(int* __restrict__ p, int n)
{
    int i = blockIdx.x * blockDim.x + threadIdx.x;
    if (i < n) p[i] = 0;
}

// convert W2,W3 (fp32) to fp16 once (for the fused kernels)
__global__ void convw_kernel(const float* __restrict__ w2,
                             const float* __restrict__ w3,
                             __half* __restrict__ o2, __half* __restrict__ o3)
{
    int i = blockIdx.x * blockDim.x + threadIdx.x;
    if (i < 96 * 96) {
        o2[i] = __float2half_rn(w2[i]);
        o3[i] = __float2half_rn(w3[i]);
    }
}

__global__ __launch_bounds__(256) void bucket_hist_kernel(
    const int* __restrict__ dst, int* __restrict__ bcnt, int E, int NB)
{
    __shared__ int lc[MAXNB];
    for (int i = threadIdx.x; i < NB; i += 256) lc[i] = 0;
    __syncthreads();
    int base = blockIdx.x * HTILE;
    #pragma unroll
    for (int j = 0; j < HTILE / 256; ++j) {
        int i = base + j * 256 + threadIdx.x;
        if (i < E) atomicAdd(&lc[dst[i] >> 6], 1);
    }
    __syncthreads();
    for (int i = threadIdx.x; i < NB; i += 256) {
        int c = lc[i];
        if (c) atomicAdd(&bcnt[i], c);
    }
}

__global__ __launch_bounds__(256) void bucket_scan_kernel(
    int* __restrict__ bbase, int* __restrict__ bcur, int NB)
{
    __shared__ int wsum[4];
    int t = threadIdx.x, lane = t & 63, wv = t >> 6;
    int vals[4], s = 0;
    #pragma unroll
    for (int j = 0; j < 4; ++j) {
        int idx = t * 4 + j;
        vals[j] = (idx < NB) ? bcur[idx] : 0;
        s += vals[j];
    }
    int inc = s;
    #pragma unroll
    for (int o = 1; o < 64; o <<= 1) {
        int u = __shfl_up(inc, o);
        if (lane >= o) inc += u;
    }
    int excl = inc - s;
    if (lane == 63) wsum[wv] = inc;
    __syncthreads();
    if (t == 0) {
        int run = 0;
        #pragma unroll
        for (int j = 0; j < 4; ++j) { int vv = wsum[j]; wsum[j] = run; run += vv; }
    }
    __syncthreads();
    int off = wsum[wv] + excl;
    #pragma unroll
    for (int j = 0; j < 4; ++j) {
        int idx = t * 4 + j;
        if (idx < NB) { bbase[idx] = off; bcur[idx] = off; off += vals[j]; }
    }
}

__global__ __launch_bounds__(256) void partition_kernel(
    const int* __restrict__ src, const int* __restrict__ dst,
    const float* __restrict__ ew, int* __restrict__ bcur,
    int2* __restrict__ ebufA, int E, int NB)
{
    __shared__ int lc[MAXNB];
    for (int i = threadIdx.x; i < NB; i += 256) lc[i] = 0;
    __syncthreads();
    int base = blockIdx.x * PTILE;
    #pragma unroll
    for (int j = 0; j < PTILE / 256; ++j) {
        int i = base + j * 256 + threadIdx.x;
        if (i < E) atomicAdd(&lc[dst[i] >> 6], 1);
    }
    __syncthreads();
    for (int i = threadIdx.x; i < NB; i += 256) {
        int c = lc[i];
        lc[i] = c ? atomicAdd(&bcur[i], c) : 0;
    }
    __syncthreads();
    #pragma unroll
    for (int j = 0; j < PTILE / 256; ++j) {
        int i = base + j * 256 + threadIdx.x;
        if (i < E) {
            int d   = dst[i];
            int bkt = d >> 6;
            int pos = atomicAdd(&lc[bkt], 1);
            ebufA[pos] = make_int2(src[i] | ((d & 63) << 26), __float_as_int(ew[i]));
        }
    }
}

__global__ __launch_bounds__(256) void csr_bucket_kernel(
    const int2* __restrict__ ebufA, const int* __restrict__ bbase,
    const int* __restrict__ bcur, int2* __restrict__ pairs,
    int* __restrict__ row_ptr, int N, int E, int NB)
{
    __shared__ int lc[64];
    int t   = threadIdx.x;
    int bkt = blockIdx.x;
    int e0  = bbase[bkt];
    int cnt = bcur[bkt] - e0;

    if (t < 64) lc[t] = 0;
    __syncthreads();
    for (int i = t; i < cnt; i += 256)
        atomicAdd(&lc[((unsigned)ebufA[e0 + i].x) >> 26], 1);
    __syncthreads();
    if (t < 64) {
        int v   = lc[t];
        int inc = v;
        #pragma unroll
        for (int o = 1; o < 64; o <<= 1) {
            int u = __shfl_up(inc, o);
            if (t >= o) inc += u;
        }
        int excl = inc - v;
        int node = (bkt << 6) + t;
        if (node < N) row_ptr[node] = e0 + excl;
        lc[t] = excl;
    }
    __syncthreads();
    for (int i = t; i < cnt; i += 256) {
        int2 p = ebufA[e0 + i];
        unsigned px = (unsigned)p.x;
        int pos = atomicAdd(&lc[px >> 26], 1);
        pairs[e0 + pos] = make_int2((int)(px & 0x03FFFFFFu), p.y);
    }
    if (bkt == NB - 1 && t == 0) row_ptr[N] = E;
}

// ---------------- Gather (standalone; final layer + fp32 path) --------------
template<bool FINAL, bool HALF, bool OHALF>
__global__ __launch_bounds__(192) void gather_kernel(
    const void* __restrict__ hbuf, const int2* __restrict__ pairs,
    const int* __restrict__ row_ptr, void* __restrict__ out,
    const float* __restrict__ xres,
    const float* __restrict__ g, const float* __restrict__ b,
    const float* __restrict__ m, const float* __restrict__ v, int N)
{
    __shared__ __attribute__((aligned(16))) float sS[96];
    __shared__ __attribute__((aligned(16))) float sT[96];
    if (FINAL) {
        int t = threadIdx.x;
        if (t < 96) {
            float s = g[t] * rsqrtf(v[t] + BN_EPS);
            sS[t] = s;
            sT[t] = b[t] - m[t] * s;
        }
        __syncthreads();
    }
    int node = blockIdx.x * 8 + threadIdx.x / 24;
    int q    = threadIdx.x % 24;
    if (node >= N) return;

    auto ld = [&](int srcR) -> float4 {
        if (HALF) {
            const __half* hp = (const __half*)hbuf + (size_t)srcR * DF + q * 4;
            float2 raw = *reinterpret_cast<const float2*>(hp);
            union { float2 f; __half2 h[2]; } u; u.f = raw;
            float2 lo = __half22float2(u.h[0]);
            float2 hi = __half22float2(u.h[1]);
            return make_float4(lo.x, lo.y, hi.x, hi.y);
        } else {
            return *(reinterpret_cast<const float4*>(
                        (const float*)hbuf + (size_t)srcR * DF) + q);
        }
    };

    int e   = row_ptr[node];
    int end = row_ptr[node + 1];
    float ax = 0.f, ay = 0.f, az = 0.f, aw = 0.f;

    auto fma1 = [&](int sr, float w) {
        float4 hv = ld(sr);
        ax = fmaf(w, hv.x, ax); ay = fmaf(w, hv.y, ay);
        az = fmaf(w, hv.z, az); aw = fmaf(w, hv.w, aw);
    };

    if (e < end && (e & 1)) {
        int2 p = pairs[e];
        fma1(p.x, __int_as_float(p.y));
        ++e;
    }
    const int4* p2 = reinterpret_cast<const int4*>(pairs);

    for (; e + 8 <= end; e += 8) {
        int h0 = e >> 1;
        int4 q0 = p2[h0 + 0];
        int4 q1 = p2[h0 + 1];
        int4 q2 = p2[h0 + 2];
        int4 q3 = p2[h0 + 3];
        float4 v0 = ld(q0.x), v1 = ld(q0.z);
        float4 v2 = ld(q1.x), v3 = ld(q1.z);
        float4 v4 = ld(q2.x), v5 = ld(q2.z);
        float4 v6 = ld(q3.x), v7 = ld(q3.z);
        float w0 = __int_as_float(q0.y), w1 = __int_as_float(q0.w);
        float w2 = __int_as_float(q1.y), w3 = __int_as_float(q1.w);
        float w4 = __int_as_float(q2.y), w5 = __int_as_float(q2.w);
        float w6 = __int_as_float(q3.y), w7 = __int_as_float(q3.w);
        ax = fmaf(w0, v0.x, ax); ay = fmaf(w0, v0.y, ay);
        az = fmaf(w0, v0.z, az); aw = fmaf(w0, v0.w, aw);
        ax = fmaf(w1, v1.x, ax); ay = fmaf(w1, v1.y, ay);
        az = fmaf(w1, v1.z, az); aw = fmaf(w1, v1.w, aw);
        ax = fmaf(w2, v2.x, ax); ay = fmaf(w2, v2.y, ay);
        az = fmaf(w2, v2.z, az); aw = fmaf(w2, v2.w, aw);
        ax = fmaf(w3, v3.x, ax); ay = fmaf(w3, v3.y, ay);
        az = fmaf(w3, v3.z, az); aw = fmaf(w3, v3.w, aw);
        ax = fmaf(w4, v4.x, ax); ay = fmaf(w4, v4.y, ay);
        az = fmaf(w4, v4.z, az); aw = fmaf(w4, v4.w, aw);
        ax = fmaf(w5, v5.x, ax); ay = fmaf(w5, v5.y, ay);
        az = fmaf(w5, v5.z, az); aw = fmaf(w5, v5.w, aw);
        ax = fmaf(w6, v6.x, ax); ay = fmaf(w6, v6.y, ay);
        az = fmaf(w6, v6.z, az); aw = fmaf(w6, v6.w, aw);
        ax = fmaf(w7, v7.x, ax); ay = fmaf(w7, v7.y, ay);
        az = fmaf(w7, v7.z, az); aw = fmaf(w7, v7.w, aw);
    }
    for (; e + 2 <= end; e += 2) {
        int4 q0 = p2[e >> 1];
        float4 v0 = ld(q0.x), v1 = ld(q0.z);
        float w0 = __int_as_float(q0.y), w1 = __int_as_float(q0.w);
        ax = fmaf(w0, v0.x, ax); ay = fmaf(w0, v0.y, ay);
        az = fmaf(w0, v0.z, az); aw = fmaf(w0, v0.w, aw);
        ax = fmaf(w1, v1.x, ax); ay = fmaf(w1, v1.y, ay);
        az = fmaf(w1, v1.z, az); aw = fmaf(w1, v1.w, aw);
    }
    if (e < end) {
        int2 p = pairs[e];
        fma1(p.x, __int_as_float(p.y));
    }

    size_t o = (size_t)node * DF + q * 4;
    if (FINAL) {
        int c = q * 4;
        float* of = (float*)out;
        float4 xv = *reinterpret_cast<const float4*>(xres + o);
        float4 s4 = *reinterpret_cast<const float4*>(sS + c);
        float4 t4 = *reinterpret_cast<const float4*>(sT + c);
        float4 r;
        r.x = fmaf(fmaxf(ax, 0.f), s4.x, t4.x) + xv.x;
        r.y = fmaf(fmaxf(ay, 0.f), s4.y, t4.y) + xv.y;
        r.z = fmaf(fmaxf(az, 0.f), s4.z, t4.z) + xv.z;
        r.w = fmaf(fmaxf(aw, 0.f), s4.w, t4.w) + xv.w;
        *reinterpret_cast<float4*>(of + o) = r;
    } else if (OHALF) {
        __half* oh = (__half*)out;
        ushort4 u;
        u.x = __half_as_ushort(__float2half_rn(ax));
        u.y = __half_as_ushort(__float2half_rn(ay));
        u.z = __half_as_ushort(__float2half_rn(az));
        u.w = __half_as_ushort(__float2half_rn(aw));
        *reinterpret_cast<ushort4*>(oh + o) = u;
    } else {
        *reinterpret_cast<float4*>((float*)out + o) =
            make_float4(ax, ay, az, aw);
    }
}

// ---------------- Fused: gather + ReLU + BN(L) + GEMM(W[L+1]) -> h fp16 ------
// r13 proven core (sWh in LDS + packed hfma2 epilogue; r14's global-W read
// regressed 50->81us: L1-hit latency ~15x LDS latency on a 96-deep dependent
// chain -- LDS staging is about latency class, not bandwidth).
// r15: 384 threads / 16 nodes per block. The fixed 18.4KB sWh is amortized
// over 2x threads: LDS/block 25.6KB but blocks/CU = min(160/25.6=6, 2048/384
// =5) = 5 -> 30 waves/CU (vs r13: 7 blocks x 3 waves = 21). Same LDS W
// latency, +43% latency hiding for the random gather.
#define FG_NODES 16
__global__ __launch_bounds__(384) void fused_gather_gemm_kernel(
    const __half* __restrict__ hin, const int2* __restrict__ pairs,
    const int* __restrict__ row_ptr, const __half* __restrict__ Wh,
    const float* __restrict__ g, const float* __restrict__ b,
    const float* __restrict__ m, const float* __restrict__ v,
    __half* __restrict__ hout, int N)
{
    __shared__ __half2 sWh[96 * 48];                         // 18.4 KB
    __shared__ float   sRow[FG_NODES][100];                  // 6.4 KB (pad 100)
    __shared__ float   sS[96], sT[96];

    const int t = threadIdx.x;
    if (t < 96) {
        float s = g[t] * rsqrtf(v[t] + BN_EPS);
        sS[t] = s;
        sT[t] = b[t] - m[t] * s;
    }
    {   // stage pre-converted fp16 W: 1152 uint4 / 384 = 3 per thread
        const uint4* srcw = reinterpret_cast<const uint4*>(Wh);
        uint4*       dstw = reinterpret_cast<uint4*>(sWh);
        #pragma unroll
        for (int i = 0; i < 3; ++i) dstw[t + 384 * i] = srcw[t + 384 * i];
    }

    const int  node  = t / 24;                // 0..15
    const int  q     = t % 24;
    const int  nodeg = blockIdx.x * FG_NODES + node;
    const bool valid = nodeg < N;

    float ax = 0.f, ay = 0.f, az = 0.f, aw = 0.f;
    if (valid) {
        auto ld = [&](int srcR) -> float4 {
            const __half* hp = hin + (size_t)srcR * DF + q * 4;
            float2 raw = *reinterpret_cast<const float2*>(hp);
            union { float2 f; __half2 h[2]; } u; u.f = raw;
            float2 lo = __half22float2(u.h[0]);
            float2 hi = __half22float2(u.h[1]);
            return make_float4(lo.x, lo.y, hi.x, hi.y);
        };
        int e   = row_ptr[nodeg];
        int end = row_ptr[nodeg + 1];
        if (e < end && (e & 1)) {
            int2 p = pairs[e];
            float4 hv = ld(p.x);
            float w = __int_as_float(p.y);
            ax = fmaf(w, hv.x, ax); ay = fmaf(w, hv.y, ay);
            az = fmaf(w, hv.z, az); aw = fmaf(w, hv.w, aw);
            ++e;
        }
        const int4* p2 = reinterpret_cast<const int4*>(pairs);
        for (; e + 8 <= end; e += 8) {
            int h0 = e >> 1;
            int4 q0 = p2[h0 + 0];
            int4 q1 = p2[h0 + 1];
            int4 q2 = p2[h0 + 2];
            int4 q3 = p2[h0 + 3];
            float4 v0 = ld(q0.x), v1 = ld(q0.z);
            float4 v2 = ld(q1.x), v3 = ld(q1.z);
            float4 v4 = ld(q2.x), v5 = ld(q2.z);
            float4 v6 = ld(q3.x), v7 = ld(q3.z);
            float w0 = __int_as_float(q0.y), w1 = __int_as_float(q0.w);
            float w2 = __int_as_float(q1.y), w3 = __int_as_float(q1.w);
            float w4 = __int_as_float(q2.y), w5 = __int_as_float(q2.w);
            float w6 = __int_as_float(q3.y), w7 = __int_as_float(q3.w);
            ax = fmaf(w0, v0.x, ax); ay = fmaf(w0, v0.y, ay);
            az = fmaf(w0, v0.z, az); aw = fmaf(w0, v0.w, aw);
            ax = fmaf(w1, v1.x, ax); ay = fmaf(w1, v1.y, ay);
            az = fmaf(w1, v1.z, az); aw = fmaf(w1, v1.w, aw);
            ax = fmaf(w2, v2.x, ax); ay = fmaf(w2, v2.y, ay);
            az = fmaf(w2, v2.z, az); aw = fmaf(w2, v2.w, aw);
            ax = fmaf(w3, v3.x, ax); ay = fmaf(w3, v3.y, ay);
            az = fmaf(w3, v3.z, az); aw = fmaf(w3, v3.w, aw);
            ax = fmaf(w4, v4.x, ax); ay = fmaf(w4, v4.y, ay);
            az = fmaf(w4, v4.z, az); aw = fmaf(w4, v4.w, aw);
            ax = fmaf(w5, v5.x, ax); ay = fmaf(w5, v5.y, ay);
            az = fmaf(w5, v5.z, az); aw = fmaf(w5, v5.w, aw);
            ax = fmaf(w6, v6.x, ax); ay = fmaf(w6, v6.y, ay);
            az = fmaf(w6, v6.z, az); aw = fmaf(w6, v6.w, aw);
            ax = fmaf(w7, v7.x, ax); ay = fmaf(w7, v7.y, ay);
            az = fmaf(w7, v7.z, az); aw = fmaf(w7, v7.w, aw);
        }
        for (; e + 2 <= end; e += 2) {
            int4 q0 = p2[e >> 1];
            float4 v0 = ld(q0.x), v1 = ld(q0.z);
            float w0 = __int_as_float(q0.y), w1 = __int_as_float(q0.w);
            ax = fmaf(w0, v0.x, ax); ay = fmaf(w0, v0.y, ay);
            az = fmaf(w0, v0.z, az); aw = fmaf(w0, v0.w, aw);
            ax = fmaf(w1, v1.x, ax); ay = fmaf(w1, v1.y, ay);
            az = fmaf(w1, v1.z, az); aw = fmaf(w1, v1.w, aw);
        }
        if (e < end) {
            int2 p = pairs[e];
            float4 hv = ld(p.x);
            float w = __int_as_float(p.y);
            ax = fmaf(w, hv.x, ax); ay = fmaf(w, hv.y, ay);
            az = fmaf(w, hv.z, az); aw = fmaf(w, hv.w, aw);
        }
    }
    __syncthreads();   // sS/sT + sWh staged; all threads present (no returns)

    // epilogue 1: relu + BN(L) -> sRow
    if (valid) {
        int c = q * 4;
        sRow[node][c + 0] = fmaf(fmaxf(ax, 0.f), sS[c + 0], sT[c + 0]);
        sRow[node][c + 1] = fmaf(fmaxf(ay, 0.f), sS[c + 1], sT[c + 1]);
        sRow[node][c + 2] = fmaf(fmaxf(az, 0.f), sS[c + 2], sT[c + 2]);
        sRow[node][c + 3] = fmaf(fmaxf(aw, 0.f), sS[c + 3], sT[c + 3]);
    }
    __syncthreads();

    // epilogue 2: GEMM row -> hout fp16, packed-fp16 accumulation (r13).
    __half2 o01 = __floats2half2_rn(0.f, 0.f);
    __half2 o23 = o01;
    for (int k = 0; k < 96; ++k) {
        __half2 w01 = sWh[k * 48 + q * 2];
        __half2 w23 = sWh[k * 48 + q * 2 + 1];
        __half2 a2  = __float2half2_rn(sRow[node][k]);
        o01 = __hfma2(a2, w01, o01);
        o23 = __hfma2(a2, w23, o23);
    }
    if (valid) {
        uint2 u;
        u.x = *reinterpret_cast<const unsigned*>(&o01);
        u.y = *reinterpret_cast<const unsigned*>(&o23);
        *reinterpret_cast<uint2*>(hout + (size_t)nodeg * DF + q * 4) = u;
    }
}

// ---------------- last-resort fallback: atomic scatter -----------------------
__global__ __launch_bounds__(256) void scatter_kernel(
    const float* __restrict__ h, const int* __restrict__ src,
    const int* __restrict__ dst, const float* __restrict__ ew,
    float* __restrict__ agg, int E)
{
    long long t = (long long)blockIdx.x * blockDim.x + threadIdx.x;
    if (t >= (long long)E * 24) return;
    int e  = (int)(t / 24);
    int cc = (int)(t % 24) * 4;
    int s  = src[e];
    int d  = dst[e];
    float w = ew[e];
    float4 hv = *reinterpret_cast<const float4*>(h + (size_t)s * DF + cc);
    float* out = agg + (size_t)d * DF + cc;
    atomicAdd(out + 0, w * hv.x);
    atomicAdd(out + 1, w * hv.y);
    atomicAdd(out + 2, w * hv.z);
    atomicAdd(out + 3, w * hv.w);
}

__global__ __launch_bounds__(256) void final_kernel(
    const float* __restrict__ agg, const float* __restrict__ x,
    const float* __restrict__ g, const float* __restrict__ b,
    const float* __restrict__ m, const float* __restrict__ v,
    float* __restrict__ out, int total4)
{
    int i = blockIdx.x * blockDim.x + threadIdx.x;
    if (i >= total4) return;
    int cc = (i % 24) * 4;
    float4 a4 = reinterpret_cast<const float4*>(agg)[i];
    float4 x4 = reinterpret_cast<const float4*>(x)[i];
    float* pa = &a4.x;
    const float* px = &x4.x;
    float4 o;
    float* po = &o.x;
    #pragma unroll
    for (int j = 0; j < 4; ++j) {
        int c = cc + j;
        float s  = g[c] * rsqrtf(v[c] + BN_EPS);
        float tt = b[c] - m[c] * s;
        float a  = pa[j] > 0.f ? pa[j] : 0.f;
        po[j] = a * s + tt + px[j];
    }
    reinterpret_cast<float4*>(out)[i] = o;
}

extern "C" void kernel_launch(void* const* d_in, const int* in_sizes, int n_in,
                              void* d_out, int out_size, void* d_ws, size_t ws_size,
                              hipStream_t stream)
{
    const float* x    = (const float*)d_in[0];
    const int*   esrc = (const int*)d_in[1];
    const int*   edst = (const int*)d_in[2];
    const float* ew   = (const float*)d_in[3];
    const float* w1   = (const float*)d_in[4];
    const float* w2   = (const float*)d_in[5];
    const float* w3   = (const float*)d_in[6];
    const float* g1 = (const float*)d_in[7],  *b1 = (const float*)d_in[8];
    const float* m1 = (const float*)d_in[9],  *v1 = (const float*)d_in[10];
    const float* g2 = (const float*)d_in[11], *b2 = (const float*)d_in[12];
    const float* m2 = (const float*)d_in[13], *v2 = (const float*)d_in[14];
    const float* g3 = (const float*)d_in[15], *b3 = (const float*)d_in[16];
    const float* m3 = (const float*)d_in[17], *v3 = (const float*)d_in[18];

    const int N  = in_sizes[0] / DF;   // 50000
    const int E  = in_sizes[1];        // 800000
    const int NB = (N + 63) >> 6;      // 782 buckets
    const size_t nbytes = (size_t)N * DF * sizeof(float);
    const size_t hh_bytes = (size_t)N * DF * 2;
    const size_t wh_bytes = (size_t)96 * 96 * 2;

    float* B = (float*)d_out;

    auto up = [](size_t s) { return (s + 255) & ~(size_t)255; };
    size_t off_agg   = 0;                               // fp32 agg OR fp16 h-buf B
    size_t off_pairs = off_agg   + up(nbytes);
    size_t off_rptr  = off_pairs + up((size_t)E * 8);
    size_t off_bbase = off_rptr  + up(((size_t)N + 1) * 4);
    size_t off_bcur  = off_bbase + up((size_t)NB * 4);
    size_t off_wh2   = off_bcur  + up((size_t)NB * 4);
    size_t off_wh3   = off_wh2   + up(wh_bytes);
    size_t off_ebufA = off_wh3   + up(wh_bytes);        // ebufA last; Hh_a aliases
    size_t need_f32  = off_ebufA + up((size_t)E * 8);
    size_t ovl       = (size_t)E * 8 > hh_bytes ? (size_t)E * 8 : hh_bytes;
    size_t need_f16  = off_ebufA + up(ovl);

    char*  ws = (char*)d_ws;
    float* A  = (float*)(ws + off_agg);

    const int gemm_grid = (N + 63) / 64;
    const bool ok = (NB <= MAXNB) && (N < (1 << 26)) && (ws_size >= need_f32);

    if (ok) {
        int2*   ebufA  = (int2*)(ws + off_ebufA);
        __half* HhA    = (__half*)(ws + off_ebufA);   // alias: ebufA dead after csr
        __half* HhB    = (__half*)(ws + off_agg);     // second fp16 h buffer
        __half* Wh2    = (__half*)(ws + off_wh2);
        __half* Wh3    = (__half*)(ws + off_wh3);
        int2*   pairs  = (int2*)(ws + off_pairs);
        int*    rowptr = (int*) (ws + off_rptr);
        int*    bbase  = (int*) (ws + off_bbase);
        int*    bcur   = (int*) (ws + off_bcur);
        const bool half_h = (ws_size >= need_f16);

        // ---- CSR build (once): zero -> hist -> scan -> partition -> sort ----
        zero_kernel<<<(NB + 255) / 256, 256, 0, stream>>>(bcur, NB);
        bucket_hist_kernel<<<(E + HTILE - 1) / HTILE, 256, 0, stream>>>(
            edst, bcur, E, NB);
        bucket_scan_kernel<<<1, 256, 0, stream>>>(bbase, bcur, NB);
        partition_kernel<<<(E + PTILE - 1) / PTILE, 256, 0, stream>>>(
            esrc, edst, ew, bcur, ebufA, E, NB);
        csr_bucket_kernel<<<NB, 256, 0, stream>>>(
            ebufA, bbase, bcur, pairs, rowptr, N, E, NB);

        const int ggrid  = (N + 7) / 8;                // standalone gathers
        const int fgrid  = (N + FG_NODES - 1) / FG_NODES;  // fused (3125)

        if (half_h) {
            convw_kernel<<<(96 * 96 + 255) / 256, 256, 0, stream>>>(
                w2, w3, Wh2, Wh3);
            // layer 1: x -> HhA (over dead ebufA)
            gemm_bn_kernel<false, false, true><<<gemm_grid, 192, 0, stream>>>(
                x, w1, nullptr, nullptr, nullptr, nullptr, HhA, N);
            // layer 2 fused: gather(HhA)+BN1+GEMM(W2) -> HhB
            fused_gather_gemm_kernel<<<fgrid, 384, 0, stream>>>(
                HhA, pairs, rowptr, Wh2, g1, b1, m1, v1, HhB, N);
            // layer 3 fused: gather(HhB)+BN2+GEMM(W3) -> HhA
            fused_gather_gemm_kernel<<<fgrid, 384, 0, stream>>>(
                HhB, pairs, rowptr, Wh3, g2, b2, m2, v2, HhA, N);
            // final: gather(HhA) + BN3 + residual -> d_out
            gather_kernel<true, true, false><<<ggrid, 192, 0, stream>>>(
                HhA, pairs, rowptr, B, x, g3, b3, m3, v3, N);
        } else {
            // fp32 everything; h in d_out (proven round-5 pipeline)
            gemm_bn_kernel<false, false, false><<<gemm_grid, 192, 0, stream>>>(
                x, w1, nullptr, nullptr, nullptr, nullptr, B, N);
            gather_kernel<false, false, false><<<ggrid, 192, 0, stream>>>(
                B, pairs, rowptr, A, nullptr, nullptr, nullptr, nullptr, nullptr, N);
            gemm_bn_kernel<true, false, false><<<gemm_grid, 192, 0, stream>>>(
                A, w2, g1, b1, m1, v1, B, N);
            gather_kernel<false, false, false><<<ggrid, 192, 0, stream>>>(
                B, pairs, rowptr, A, nullptr, nullptr, nullptr, nullptr, nullptr, N);
            gemm_bn_kernel<true, false, false><<<gemm_grid, 192, 0, stream>>>(
                A, w3, g2, b2, m2, v2, A, N);
            gather_kernel<true, false, false><<<ggrid, 192, 0, stream>>>(
                A, pairs, rowptr, B, x, g3, b3, m3, v3, N);
        }
    } else {
        // last-resort: atomic scatter path
        const long long st     = (long long)E * 24;
        const int scatter_grid = (int)((st + 255) / 256);
        const int total4       = N * 24;
        const int final_grid   = (total4 + 255) / 256;

        hipMemsetAsync(A, 0, nbytes, stream);
        gemm_bn_kernel<false, false, false><<<gemm_grid, 192, 0, stream>>>(
            x, w1, nullptr, nullptr, nullptr, nullptr, B, N);
        scatter_kernel<<<scatter_grid, 256, 0, stream>>>(B, esrc, edst, ew, A, E);

        gemm_bn_kernel<true, false, false><<<gemm_grid, 192, 0, stream>>>(
            A, w2, g1, b1, m1, v1, B, N);
        hipMemsetAsync(A, 0, nbytes, stream);
        scatter_kernel<<<scatter_grid, 256, 0, stream>>>(B, esrc, edst, ew, A, E);

        gemm_bn_kernel<true, false, false><<<gemm_grid, 192, 0, stream>>>(
            A, w3, g2, b2, m2, v2, B, N);
        hipMemsetAsync(A, 0, nbytes, stream);
        scatter_kernel<<<scatter_grid, 256, 0, stream>>>(B, esrc, edst, ew, A, E);

        final_kernel<<<final_grid, 256, 0, stream>>>(
            A, x, g3, b3, m3, v3, (float*)d_out, total4);
    }
}